// Round 6
// baseline (4302.026 us; speedup 1.0000x reference)
//
#include <hip/hip_runtime.h>
#include <stdint.h>
#include <stddef.h>

// ---------------- problem constants ----------------
#define BB 2
#define SS 2048
#define DD 4096
#define NH 32
#define NKV 8
#define HD 128
#define QDIM 4096
#define KVDIM 1024
#define NQKV 6144
#define KTILES 128  // K / 32
// 1/sqrt(128) * log2(e): Q pre-scale so softmax exp is a single v_exp_f32 (2^x)
#define QK_SCALE_L2E 0.12751744f

typedef __bf16 bf16;
typedef __bf16 bf16x8 __attribute__((ext_vector_type(8)));
typedef __bf16 bf16x4 __attribute__((ext_vector_type(4)));
typedef float f32x4 __attribute__((ext_vector_type(4)));

#define MFMA16(a, b, c) __builtin_amdgcn_mfma_f32_16x16x32_bf16((a), (b), (c), 0, 0, 0)
#define BAR() __builtin_amdgcn_s_barrier()
#define VMW5() asm volatile("s_waitcnt vmcnt(5)" ::: "memory")
#define VMW4() asm volatile("s_waitcnt vmcnt(4)" ::: "memory")

typedef __attribute__((address_space(1))) void GASV;
typedef __attribute__((address_space(3))) void LASV;

__device__ __forceinline__ void gload_lds16(const void* g, void* l) {
    __builtin_amdgcn_global_load_lds((GASV*)g, (LASV*)l, 16, 0, 0);
}

__device__ __forceinline__ float fexp2(float x) {
    float r;
    asm("v_exp_f32 %0, %1" : "=v"(r) : "v"(x));
    return r;
}

// ---------------- fp32 -> bf16 convert (x) ----------------
__global__ __launch_bounds__(256) void k_cvt_x(const float* __restrict__ in,
                                               bf16* __restrict__ out) {
    size_t i = ((size_t)blockIdx.x * 256 + threadIdx.x) * 8;
    const float4 a = *(const float4*)(in + i);
    const float4 b = *(const float4*)(in + i + 4);
    bf16x8 v;
    v[0] = (bf16)a.x; v[1] = (bf16)a.y; v[2] = (bf16)a.z; v[3] = (bf16)a.w;
    v[4] = (bf16)b.x; v[5] = (bf16)b.y; v[6] = (bf16)b.z; v[7] = (bf16)b.w;
    *(bf16x8*)(out + i) = v;
}

// ---------------- transpose + convert: in[R][C] f32 -> out[C][R] bf16 ----------------
__global__ __launch_bounds__(256) void k_tr_cvt(const float* __restrict__ in,
                                                bf16* __restrict__ out, int R, int C) {
    __shared__ float tile[64][65];
    const int t = threadIdx.x;
    const int tx = t & 15, ty = t >> 4;
    const int r0 = blockIdx.y * 64, c0 = blockIdx.x * 64;
#pragma unroll
    for (int p = 0; p < 4; ++p) {
        const float4 v = *(const float4*)(in + (size_t)(r0 + p * 16 + ty) * C + c0 + tx * 4);
        tile[p * 16 + ty][tx * 4 + 0] = v.x;
        tile[p * 16 + ty][tx * 4 + 1] = v.y;
        tile[p * 16 + ty][tx * 4 + 2] = v.z;
        tile[p * 16 + ty][tx * 4 + 3] = v.w;
    }
    __syncthreads();
#pragma unroll
    for (int p = 0; p < 4; ++p) {
        const int oc = c0 + p * 16 + ty;
        bf16x4 pk;
#pragma unroll
        for (int j = 0; j < 4; ++j) pk[j] = (bf16)tile[tx * 4 + j][p * 16 + ty];
        *(bf16x4*)(out + (size_t)oc * R + r0 + tx * 4) = pk;
    }
}

// ================= 256x256 GEMM core, BK=32, 64KB LDS, 2 blocks/CU =================
// 512 thr / 8 waves (2M x 4N). r5's validated dataflow (p1: read B1(tau); p2: read
// A1(tau); p4: read A0/B0(tau+1); no reg overwritten before last consumer), BK
// halved so LDS = 2dbuf x 2half x 128rows x 32k x 2B x 2(A,B) = 64KB -> 2 blocks/CU
// resident (launch_bounds(512,4)). Cross-block wave overlap hides barrier stalls;
// qkv's 384 blocks are all co-resident (no tail round). Waits re-derived for
// 1 gload_lds per stage: vmcnt(5)@p3 (covers p4's A0/B0(tau+1) reads),
// vmcnt(4)@p4 (covers next p1/p2's B1/A1 reads). Row stride 64B (4 chunks);
// swizzle slot = chunk ^ ((row>>1)&3) (2-way bank alias = free), applied on the
// pre-swizzled global source (write side) and on ds_read (read side).

__device__ __forceinline__ void stage_half(char* ldsRegion, const bf16* gsrc) {
    const int t = threadIdx.x;
    const int wid = t >> 6;
    const int off = t * 16;                // 8KB half staged by 512 threads
    const int row = off >> 6;              // 64B rows
    const int pc = (off >> 4) & 3;         // phys chunk
    const int lc = pc ^ ((row >> 1) & 3);  // logical chunk fetched into phys slot
    gload_lds16(gsrc + (size_t)row * 4096 + lc * 8, ldsRegion + wid * 1024);
}

__device__ __forceinline__ void gemm256(const bf16* __restrict__ At,
                                        const bf16* __restrict__ Bt,
                                        char* LB, f32x4 acc[8][4]) {
    const int tid = threadIdx.x, lane = tid & 63, wid = tid >> 6;
    const int wm = wid >> 2, wn = wid & 3;
    const int l15 = lane & 15, l4 = lane >> 4;

    const f32x4 vz = {0.f, 0.f, 0.f, 0.f};
#pragma unroll
    for (int m = 0; m < 8; ++m)
#pragma unroll
        for (int n = 0; n < 4; ++n) acc[m][n] = vz;

    auto Areg = [&](int db, int h) -> char* { return LB + db * 16384 + h * 8192; };
    auto Breg = [&](int db, int h) -> char* { return LB + 32768 + db * 16384 + h * 8192; };

    bf16x8 RA[4], RAb[4], RB0[2], RB1[2];

    auto loadA = [&](bf16x8 dst[4], int db, int h) {
        char* base = Areg(db, h);
#pragma unroll
        for (int mf = 0; mf < 4; ++mf) {
            const int row = wm * 64 + mf * 16 + l15;
            const int slot = l4 ^ ((row >> 1) & 3);
            dst[mf] = *(const bf16x8*)(base + row * 64 + slot * 16);
        }
    };
    auto loadB = [&](bf16x8 dst[2], int db, int h) {
        char* base = Breg(db, h);
#pragma unroll
        for (int nf = 0; nf < 2; ++nf) {
            const int row = wn * 32 + nf * 16 + l15;
            const int slot = l4 ^ ((row >> 1) & 3);
            dst[nf] = *(const bf16x8*)(base + row * 64 + slot * 16);
        }
    };
    auto stA = [&](int tau, int h) {
        stage_half(Areg(tau & 1, h), At + (size_t)(h * 128) * 4096 + tau * 32);
    };
    auto stB = [&](int tau, int h) {
        stage_half(Breg(tau & 1, h), Bt + (size_t)(h * 128) * 4096 + tau * 32);
    };
    auto mma = [&](bf16x8 A[4], bf16x8 B[2], int mb, int nb) {
        __builtin_amdgcn_s_setprio(1);
#pragma unroll
        for (int mf = 0; mf < 4; ++mf)
#pragma unroll
            for (int nf = 0; nf < 2; ++nf)
                acc[mb + mf][nb + nf] = MFMA16(A[mf], B[nf], acc[mb + mf][nb + nf]);
        __builtin_amdgcn_s_setprio(0);
    };

    // ---- prologue: stage tiles 0,1 (8 loads/thread); vmcnt(4) => tile0 landed
    stA(0, 0); stB(0, 0); stB(0, 1); stA(0, 1);
    stA(1, 0); stB(1, 0); stB(1, 1); stA(1, 1);
    VMW4();
    BAR();
    loadA(RA, 0, 0); loadB(RB0, 0, 0);

    // ---- main loop: tiles 0..125; stages tiles 2..127
#pragma unroll 1
    for (int tau = 0; tau < KTILES - 2; ++tau) {
        const int db = tau & 1, ndb = db ^ 1;
        // p1: read tau.B1 ; stage (tau+2).A0 ; MFMA (A0,B0)
        loadB(RB1, db, 1);
        stA(tau + 2, 0);
        BAR();
        mma(RA, RB0, 0, 0);
        BAR();
        // p2: read tau.A1 ; stage (tau+2).B0 ; MFMA (A0,B1)
        loadA(RAb, db, 1);
        stB(tau + 2, 0);
        BAR();
        mma(RA, RB1, 0, 2);
        BAR();
        // p3: stage (tau+2).B1 ; vmcnt(5) ; MFMA (A1,B0)
        stB(tau + 2, 1);
        VMW5();
        BAR();
        mma(RAb, RB0, 4, 0);
        BAR();
        // p4: read (tau+1).{A0,B0} ; stage (tau+2).A1 ; vmcnt(4) ; MFMA (A1,B1)
        loadA(RA, ndb, 0);
        loadB(RB0, ndb, 0);
        stA(tau + 2, 1);
        VMW4();
        BAR();
        mma(RAb, RB1, 4, 2);
        BAR();
    }

    // ---- tail: tiles 126,127 fully staged; one drain, then barrier-free compute
    asm volatile("s_waitcnt vmcnt(0)" ::: "memory");
    BAR();
#pragma unroll 1
    for (int tau = KTILES - 2; tau < KTILES; ++tau) {
        const int db = tau & 1, ndb = db ^ 1;
        loadB(RB1, db, 1);
        mma(RA, RB0, 0, 0);
        loadA(RAb, db, 1);
        mma(RA, RB1, 0, 2);
        mma(RAb, RB0, 4, 0);
        if (tau < KTILES - 1) { loadA(RA, ndb, 0); loadB(RB0, ndb, 0); }
        mma(RAb, RB1, 4, 2);
    }
}

// bijective XCD-chunk swizzle (nwg % 8 == 0 for all our grids)
__device__ __forceinline__ void xcd_swizzle(int gx, int& bx, int& by) {
    const int nwg = gx * gridDim.y;
    int lin = by * gx + bx;
    lin = (lin & 7) * (nwg >> 3) + (lin >> 3);
    bx = lin % gx;
    by = lin / gx;
}

// ---------------- GEMM 1: xqkv = x @ wqkv, fused RoPE, writes Q,K,V^T ----------------
__global__ __launch_bounds__(512, 4) void k_gemm_qkv(const bf16* __restrict__ A,
                                                     const bf16* __restrict__ Bt,
                                                     const float* __restrict__ fc,
                                                     bf16* __restrict__ Qb,
                                                     bf16* __restrict__ Kb,
                                                     bf16* __restrict__ VTb) {
    __shared__ __align__(16) char LB[65536];
    f32x4 acc[8][4];
    int bx = blockIdx.x, by = blockIdx.y;
    xcd_swizzle(NQKV / 256, bx, by);
    gemm256(A + (size_t)by * 256 * 4096, Bt + (size_t)bx * 256 * 4096, LB, acc);

    const int tid = threadIdx.x, lane = tid & 63, wid = tid >> 6;
    const int wm = wid >> 2, wn = wid & 3;
    const int l15 = lane & 15, l4 = lane >> 4;
    const int n0r = bx * 256;  // block-uniform region selector (regions 1024-aligned)
#pragma unroll
    for (int mf = 0; mf < 8; ++mf) {
        const int rowbase = by * 256 + (mf >> 2) * 128 + wm * 64 + (mf & 3) * 16 + l4 * 4;
#pragma unroll
        for (int nf = 0; nf < 4; ++nf) {
            const int col = n0r + (nf >> 1) * 128 + wn * 32 + (nf & 1) * 16 + l15;
            f32x4 v = acc[mf][nf];
            if (n0r < QDIM + KVDIM) {
                // Q or K: RoPE. Paired column col^1 lives in lane^1 (C-layout col=lane&15).
                const int d = col & (HD - 1);
                const int dp = d & ~1;
                const float sgn = (d & 1) ? 1.f : -1.f;
#pragma unroll
                for (int r = 0; r < 4; ++r) {
                    const int row = rowbase + r;
                    const int s = row & (SS - 1);
                    const float2 sc = *(const float2*)(fc + s * HD + dp);  // (sin, cos)
                    const float partner = __shfl_xor(v[r], 1);
                    float res = v[r] * sc.y + sgn * partner * sc.x;
                    if (n0r < QDIM) {
                        res *= QK_SCALE_L2E;
                        Qb[(size_t)row * QDIM + col] = (bf16)res;
                    } else {
                        Kb[(size_t)row * KVDIM + (col - QDIM)] = (bf16)res;
                    }
                }
            } else {
                // V: write transposed [b][kvh][d][s]; 4 consecutive s -> 8B store
                const int hdv = col - (QDIM + KVDIM);
                const int kvh = hdv >> 7, dd = hdv & (HD - 1);
                const int bb = rowbase >> 11, s = rowbase & (SS - 1);
                bf16x4 pk;
#pragma unroll
                for (int r = 0; r < 4; ++r) pk[r] = (bf16)v[r];
                *(bf16x4*)(VTb + ((size_t)((bb * NKV + kvh) * HD + dd)) * SS + s) = pk;
            }
        }
    }
}

// ---------------- GEMM 2: out = attn @ wo (f32 output) ----------------
__global__ __launch_bounds__(512, 4) void k_gemm_out(const bf16* __restrict__ A,
                                                     const bf16* __restrict__ Bt,
                                                     float* __restrict__ out) {
    __shared__ __align__(16) char LB[65536];
    f32x4 acc[8][4];
    int bx = blockIdx.x, by = blockIdx.y;
    xcd_swizzle(DD / 256, bx, by);
    gemm256(A + (size_t)by * 256 * 4096, Bt + (size_t)bx * 256 * 4096, LB, acc);

    const int tid = threadIdx.x, lane = tid & 63, wid = tid >> 6;
    const int wm = wid >> 2, wn = wid & 3;
    const int l15 = lane & 15, l4 = lane >> 4;
#pragma unroll
    for (int mf = 0; mf < 8; ++mf) {
        const int row = by * 256 + (mf >> 2) * 128 + wm * 64 + (mf & 3) * 16 + l4 * 4;
#pragma unroll
        for (int nf = 0; nf < 4; ++nf) {
            const int col = bx * 256 + (nf >> 1) * 128 + wn * 32 + (nf & 1) * 16 + l15;
#pragma unroll
            for (int r = 0; r < 4; ++r) out[(size_t)(row + r) * DD + col] = acc[mf][nf][r];
        }
    }
}

// ---------------- flash attention (r2 structure + XCD swizzle) ----------------
__global__ __launch_bounds__(256, 2) void k_attn(const bf16* __restrict__ Qb,
                                                 const bf16* __restrict__ Kb,
                                                 const bf16* __restrict__ VTb,
                                                 bf16* __restrict__ Ob) {
    __shared__ __align__(16) bf16 Ks[64 * 128];
    __shared__ __align__(16) bf16 Vs[128 * 64];
    __shared__ __align__(16) bf16 Ps[4][32 * 88];
    // swizzle 512 blocks -> 64 consecutive per XCD (2 kvh-groups' K/V L2-resident)
    int lin = (blockIdx.z * NH + blockIdx.y) * 8 + blockIdx.x;
    lin = (lin & 7) * 64 + (lin >> 3);
    const int jj = lin & 7, h = (lin >> 3) & (NH - 1), b = lin >> 8;
    const int kvh = h >> 2;
    const int tid = threadIdx.x, lane = tid & 63, w = tid >> 6;
    const int l15 = lane & 15, l4 = lane >> 4;

    const bf16* Kg = Kb + (size_t)b * SS * KVDIM + kvh * HD;
    const bf16* Vg = VTb + (size_t)(b * NKV + kvh) * HD * SS;

    int4 kreg[4], vreg[4];
    const f32x4 vz = {0.f, 0.f, 0.f, 0.f};

    auto issue_kv = [&](int t) {
#pragma unroll
        for (int i = 0; i < 4; ++i) {
            const int off = i * 4096 + tid * 16;
            const int row = off >> 8;
            const int cc = (off >> 4) & 15;
            kreg[i] = *(const int4*)((const char*)(Kg + (size_t)(t * 64 + row) * KVDIM) + cc * 16);
        }
#pragma unroll
        for (int i = 0; i < 4; ++i) {
            const int off = i * 4096 + tid * 16;
            const int row = off >> 7;
            const int cc = (off >> 4) & 7;
            vreg[i] = *(const int4*)((const char*)(Vg + (size_t)row * SS + t * 64) + cc * 16);
        }
    };

#pragma unroll 1
    for (int pj = 0; pj < 2; ++pj) {
        const int j = pj ? (15 - jj) : jj;
        const int q0 = j * 128;
        const int nt = 2 * j + 2;

        bf16x8 qf[2][4];
#pragma unroll
        for (int m = 0; m < 2; ++m) {
            const int qrow = q0 + w * 32 + m * 16 + l15;
            const bf16* qb = Qb + ((size_t)(b * SS + qrow) << 12) + h * HD + l4 * 8;
#pragma unroll
            for (int kc = 0; kc < 4; ++kc) qf[m][kc] = *(const bf16x8*)(qb + kc * 32);
        }

        f32x4 o[2][8];
#pragma unroll
        for (int m = 0; m < 2; ++m)
#pragma unroll
            for (int df = 0; df < 8; ++df) o[m][df] = vz;
        float m_run[2][4], l_run[2][4];
#pragma unroll
        for (int m = 0; m < 2; ++m)
#pragma unroll
            for (int r = 0; r < 4; ++r) { m_run[m][r] = -1e30f; l_run[m][r] = 0.f; }

        issue_kv(0);

        for (int t = 0; t < nt; ++t) {
            __syncthreads();
#pragma unroll
            for (int i = 0; i < 4; ++i) {
                const int off = i * 4096 + tid * 16;
                const int row = off >> 8;
                const int cc = (off >> 4) & 15;
                const int lc = cc ^ (row & 7);
                *(int4*)((char*)Ks + row * 256 + lc * 16) = kreg[i];
            }
#pragma unroll
            for (int i = 0; i < 4; ++i) {
                const int off = i * 4096 + tid * 16;
                const int row = off >> 7;
                const int cc = (off >> 4) & 7;
                const int lc = cc ^ (row & 7);
                *(int4*)((char*)Vs + row * 128 + lc * 16) = vreg[i];
            }
            __syncthreads();

            if (t + 1 < nt) issue_kv(t + 1);

            f32x4 sa[2][4];
#pragma unroll
            for (int m = 0; m < 2; ++m)
#pragma unroll
                for (int n = 0; n < 4; ++n) sa[m][n] = vz;
            __builtin_amdgcn_s_setprio(1);
#pragma unroll
            for (int kc = 0; kc < 4; ++kc)
#pragma unroll
                for (int n = 0; n < 4; ++n) {
                    const int krow = n * 16 + l15;
                    const int cc = kc * 4 + l4;
                    const bf16x8 kf =
                        *(const bf16x8*)((const char*)Ks + (krow << 8) + ((cc ^ (krow & 7)) << 4));
                    sa[0][n] = MFMA16(qf[0][kc], kf, sa[0][n]);
                    sa[1][n] = MFMA16(qf[1][kc], kf, sa[1][n]);
                }
            __builtin_amdgcn_s_setprio(0);

            if (t >= 2 * j) {
#pragma unroll
                for (int m = 0; m < 2; ++m)
#pragma unroll
                    for (int n = 0; n < 4; ++n)
#pragma unroll
                        for (int r = 0; r < 4; ++r) {
                            const int col = t * 64 + n * 16 + l15;
                            const int qr = q0 + w * 32 + m * 16 + l4 * 4 + r;
                            if (col > qr) sa[m][n][r] = -1e30f;
                        }
            }

#pragma unroll
            for (int m = 0; m < 2; ++m)
#pragma unroll
                for (int r = 0; r < 4; ++r) {
                    float mx = fmaxf(fmaxf(sa[m][0][r], sa[m][1][r]),
                                     fmaxf(sa[m][2][r], sa[m][3][r]));
#pragma unroll
                    for (int mk = 1; mk <= 8; mk <<= 1) mx = fmaxf(mx, __shfl_xor(mx, mk));
                    const float mn = fmaxf(m_run[m][r], mx);
                    const float alpha = fexp2(m_run[m][r] - mn);
                    m_run[m][r] = mn;
                    float rs = 0.f;
#pragma unroll
                    for (int n = 0; n < 4; ++n) {
                        const float p = fexp2(sa[m][n][r] - mn);
                        sa[m][n][r] = p;
                        rs += p;
                    }
#pragma unroll
                    for (int mk = 1; mk <= 8; mk <<= 1) rs += __shfl_xor(rs, mk);
                    l_run[m][r] = l_run[m][r] * alpha + rs;
#pragma unroll
                    for (int df = 0; df < 8; ++df) o[m][df][r] *= alpha;
                }

#pragma unroll
            for (int m = 0; m < 2; ++m)
#pragma unroll
                for (int n = 0; n < 4; ++n)
#pragma unroll
                    for (int r = 0; r < 4; ++r)
                        Ps[w][(m * 16 + l4 * 4 + r) * 88 + n * 16 + l15] = (bf16)sa[m][n][r];

            bf16x8 pf0[2], pf1[2];
#pragma unroll
            for (int ks = 0; ks < 2; ++ks) {
                pf0[ks] = *(const bf16x8*)(&Ps[w][l15 * 88 + ks * 32 + l4 * 8]);
                pf1[ks] = *(const bf16x8*)(&Ps[w][(16 + l15) * 88 + ks * 32 + l4 * 8]);
            }

            __builtin_amdgcn_s_setprio(1);
#pragma unroll
            for (int df = 0; df < 8; ++df)
#pragma unroll
                for (int ks = 0; ks < 2; ++ks) {
                    const int vrow = df * 16 + l15;
                    const int cc = ks * 4 + l4;
                    const bf16x8 vf =
                        *(const bf16x8*)((const char*)Vs + (vrow << 7) + ((cc ^ (vrow & 7)) << 4));
                    o[0][df] = MFMA16(pf0[ks], vf, o[0][df]);
                    o[1][df] = MFMA16(pf1[ks], vf, o[1][df]);
                }
            __builtin_amdgcn_s_setprio(0);
        }

#pragma unroll
        for (int m = 0; m < 2; ++m)
#pragma unroll
            for (int r = 0; r < 4; ++r) {
                const float inv = 1.f / l_run[m][r];
                const size_t row = (size_t)(b * SS + q0 + w * 32 + m * 16 + l4 * 4 + r);
#pragma unroll
                for (int df = 0; df < 8; ++df)
                    Ob[(row << 12) + h * HD + df * 16 + l15] = (bf16)(o[m][df][r] * inv);
            }
    }
}

// ---------------- launcher ----------------
extern "C" void kernel_launch(void* const* d_in, const int* in_sizes, int n_in,
                              void* d_out, int out_size, void* d_ws, size_t ws_size,
                              hipStream_t stream) {
    const float* x    = (const float*)d_in[0];
    const float* fc   = (const float*)d_in[1];
    const float* wqkv = (const float*)d_in[2];
    const float* wo   = (const float*)d_in[3];

    char* wsp = (char*)d_ws;
    const size_t MB = (size_t)1 << 20;
    bf16* xb    = (bf16*)(wsp);              // 32MB
    bf16* wqkvT = (bf16*)(wsp + 32 * MB);    // 48MB
    bf16* woT   = (bf16*)(wsp + 32 * MB);    // 32MB (aliases wqkvT; written after gemm_qkv)
    bf16* Qb    = (bf16*)(wsp + 80 * MB);    // 32MB
    bf16* Kb    = (bf16*)(wsp + 112 * MB);   //  8MB
    bf16* VTb   = (bf16*)(wsp + 120 * MB);   //  8MB
    bf16* Ab    = (bf16*)(wsp);              // attn out bf16 (aliases xb)
    float* out  = (float*)d_out;

    k_cvt_x<<<8192, 256, 0, stream>>>(x, xb);
    k_tr_cvt<<<dim3(NQKV / 64, DD / 64), 256, 0, stream>>>(wqkv, wqkvT, DD, NQKV);
    k_gemm_qkv<<<dim3(NQKV / 256, (BB * SS) / 256), 512, 0, stream>>>(xb, wqkvT, fc, Qb, Kb, VTb);
    k_tr_cvt<<<dim3(DD / 64, QDIM / 64), 256, 0, stream>>>(wo, woT, QDIM, DD);
    k_attn<<<dim3(8, NH, BB), 256, 0, stream>>>(Qb, Kb, VTb, Ab);
    k_gemm_out<<<dim3(DD / 256, (BB * SS) / 256), 512, 0, stream>>>(Ab, woT, out);
}

// Round 7
// 571.068 us; speedup vs baseline: 7.5333x; 7.5333x over previous
//
#include <hip/hip_runtime.h>
#include <stdint.h>
#include <stddef.h>

// ---------------- problem constants ----------------
#define BB 2
#define SS 2048
#define DD 4096
#define NH 32
#define NKV 8
#define HD 128
#define QDIM 4096
#define KVDIM 1024
#define NQKV 6144
#define NTILES 64  // K / 64
// 1/sqrt(128) * log2(e): Q pre-scale so softmax exp is a single v_exp_f32 (2^x)
#define QK_SCALE_L2E 0.12751744f

typedef __bf16 bf16;
typedef __bf16 bf16x8 __attribute__((ext_vector_type(8)));
typedef __bf16 bf16x4 __attribute__((ext_vector_type(4)));
typedef float f32x4 __attribute__((ext_vector_type(4)));

#define MFMA16(a, b, c) __builtin_amdgcn_mfma_f32_16x16x32_bf16((a), (b), (c), 0, 0, 0)
#define BAR() __builtin_amdgcn_s_barrier()
#define VMW10() asm volatile("s_waitcnt vmcnt(10)" ::: "memory")
#define VMW8() asm volatile("s_waitcnt vmcnt(8)" ::: "memory")
#define VMW7() asm volatile("s_waitcnt vmcnt(7)" ::: "memory")

typedef __attribute__((address_space(1))) void GASV;
typedef __attribute__((address_space(3))) void LASV;

__device__ __forceinline__ void gload_lds16(const void* g, void* l) {
    __builtin_amdgcn_global_load_lds((GASV*)g, (LASV*)l, 16, 0, 0);
}

__device__ __forceinline__ float fexp2(float x) {
    float r;
    asm("v_exp_f32 %0, %1" : "=v"(r) : "v"(x));
    return r;
}

// ---------------- fp32 -> bf16 convert (x) ----------------
__global__ __launch_bounds__(256) void k_cvt_x(const float* __restrict__ in,
                                               bf16* __restrict__ out) {
    size_t i = ((size_t)blockIdx.x * 256 + threadIdx.x) * 8;
    const float4 a = *(const float4*)(in + i);
    const float4 b = *(const float4*)(in + i + 4);
    bf16x8 v;
    v[0] = (bf16)a.x; v[1] = (bf16)a.y; v[2] = (bf16)a.z; v[3] = (bf16)a.w;
    v[4] = (bf16)b.x; v[5] = (bf16)b.y; v[6] = (bf16)b.z; v[7] = (bf16)b.w;
    *(bf16x8*)(out + i) = v;
}

// ---------------- transpose + convert: in[R][C] f32 -> out[C][R] bf16 ----------------
__global__ __launch_bounds__(256) void k_tr_cvt(const float* __restrict__ in,
                                                bf16* __restrict__ out, int R, int C) {
    __shared__ float tile[64][65];
    const int t = threadIdx.x;
    const int tx = t & 15, ty = t >> 4;
    const int r0 = blockIdx.y * 64, c0 = blockIdx.x * 64;
#pragma unroll
    for (int p = 0; p < 4; ++p) {
        const float4 v = *(const float4*)(in + (size_t)(r0 + p * 16 + ty) * C + c0 + tx * 4);
        tile[p * 16 + ty][tx * 4 + 0] = v.x;
        tile[p * 16 + ty][tx * 4 + 1] = v.y;
        tile[p * 16 + ty][tx * 4 + 2] = v.z;
        tile[p * 16 + ty][tx * 4 + 3] = v.w;
    }
    __syncthreads();
#pragma unroll
    for (int p = 0; p < 4; ++p) {
        const int oc = c0 + p * 16 + ty;
        bf16x4 pk;
#pragma unroll
        for (int j = 0; j < 4; ++j) pk[j] = (bf16)tile[tx * 4 + j][p * 16 + ty];
        *(bf16x4*)(out + (size_t)oc * R + r0 + tx * 4) = pk;
    }
}

// ---- shared staging helper: 128-row x 64-k half (16KB), 2 loads/thread ----
__device__ __forceinline__ void stage_half(char* ldsRegion, const bf16* gsrc) {
    const int t = threadIdx.x;
    const int wid = t >> 6;
#pragma unroll
    for (int i = 0; i < 2; ++i) {
        const int off = i * 8192 + t * 16;
        const int row = off >> 7;          // 128B rows
        const int pc = (off >> 4) & 7;     // phys chunk
        const int lc = pc ^ (row & 7);     // logical chunk fetched into phys slot
        gload_lds16(gsrc + (size_t)row * 4096 + lc * 8,
                    ldsRegion + i * 8192 + wid * 1024);
    }
}

// ================= 256x256 core (r5-validated, for gemm_out) =================
__device__ __forceinline__ void gemm256(const bf16* __restrict__ At,
                                        const bf16* __restrict__ Bt,
                                        char* LB, f32x4 acc[8][4]) {
    const int tid = threadIdx.x, lane = tid & 63, wid = tid >> 6;
    const int wm = wid >> 2, wn = wid & 3;
    const int l15 = lane & 15, l4 = lane >> 4;

    const f32x4 vz = {0.f, 0.f, 0.f, 0.f};
#pragma unroll
    for (int m = 0; m < 8; ++m)
#pragma unroll
        for (int n = 0; n < 4; ++n) acc[m][n] = vz;

    auto Areg = [&](int db, int h) -> char* { return LB + db * 32768 + h * 16384; };
    auto Breg = [&](int db, int h) -> char* { return LB + 65536 + db * 32768 + h * 16384; };

    bf16x8 RA[2][4], RAb[2][4], RB0[2][2], RB1[2][2];

    auto loadA = [&](bf16x8 dst[2][4], int db, int h) {
        char* base = Areg(db, h);
#pragma unroll
        for (int kk = 0; kk < 2; ++kk)
#pragma unroll
            for (int mf = 0; mf < 4; ++mf) {
                const int row = wm * 64 + mf * 16 + l15;
                const int cc = kk * 4 + l4;
                dst[kk][mf] = *(const bf16x8*)(base + row * 128 + ((cc ^ (row & 7)) << 4));
            }
    };
    auto loadB = [&](bf16x8 dst[2][2], int db, int h) {
        char* base = Breg(db, h);
#pragma unroll
        for (int kk = 0; kk < 2; ++kk)
#pragma unroll
            for (int nf = 0; nf < 2; ++nf) {
                const int row = wn * 32 + nf * 16 + l15;
                const int cc = kk * 4 + l4;
                dst[kk][nf] = *(const bf16x8*)(base + row * 128 + ((cc ^ (row & 7)) << 4));
            }
    };
    auto stA = [&](int tau, int h) {
        stage_half(Areg(tau & 1, h), At + (size_t)(h * 128) * 4096 + tau * 64);
    };
    auto stB = [&](int tau, int h) {
        stage_half(Breg(tau & 1, h), Bt + (size_t)(h * 128) * 4096 + tau * 64);
    };
    auto mma = [&](bf16x8 A[2][4], bf16x8 B[2][2], int mb, int nb) {
        __builtin_amdgcn_s_setprio(1);
#pragma unroll
        for (int kk = 0; kk < 2; ++kk)
#pragma unroll
            for (int mf = 0; mf < 4; ++mf)
#pragma unroll
                for (int nf = 0; nf < 2; ++nf)
                    acc[mb + mf][nb + nf] = MFMA16(A[kk][mf], B[kk][nf], acc[mb + mf][nb + nf]);
        __builtin_amdgcn_s_setprio(0);
    };

    stA(0, 0); stB(0, 0); stB(0, 1); stA(0, 1);
    stA(1, 0); stB(1, 0); stB(1, 1); stA(1, 1);
    VMW8();
    BAR();
    loadA(RA, 0, 0); loadB(RB0, 0, 0);

#pragma unroll 1
    for (int tau = 0; tau < NTILES - 2; ++tau) {
        const int db = tau & 1, ndb = db ^ 1;
        loadB(RB1, db, 1);
        stA(tau + 2, 0);
        BAR();
        mma(RA, RB0, 0, 0);
        BAR();
        loadA(RAb, db, 1);
        stB(tau + 2, 0);
        BAR();
        mma(RA, RB1, 0, 2);
        BAR();
        stB(tau + 2, 1);
        VMW10();
        BAR();
        mma(RAb, RB0, 4, 0);
        BAR();
        loadA(RA, ndb, 0);
        loadB(RB0, ndb, 0);
        stA(tau + 2, 1);
        VMW8();
        BAR();
        mma(RAb, RB1, 4, 2);
        BAR();
    }

    asm volatile("s_waitcnt vmcnt(0)" ::: "memory");
    BAR();
#pragma unroll 1
    for (int tau = NTILES - 2; tau < NTILES; ++tau) {
        const int db = tau & 1, ndb = db ^ 1;
        loadB(RB1, db, 1);
        mma(RA, RB0, 0, 0);
        loadA(RAb, db, 1);
        mma(RA, RB1, 0, 2);
        mma(RAb, RB0, 4, 0);
        if (tau < NTILES - 1) { loadA(RA, ndb, 0); loadB(RB0, ndb, 0); }
        mma(RAb, RB1, 4, 2);
    }
}

// ================= 256x192 core (qkv: 512 blocks = 2 exact rounds, no tail) =====
// 8 waves (2M x 4N); per-wave C = 128 rows x 48 cols (3 n-frags, split 2+1).
// A staged in two 128-row halves (r5 stage_half); B staged whole (192x64 = 24KB,
// 3 loads/thread). Stage rotation per tile tau (for tile tau+2, same-parity buf):
// p1: A0'' ; p2: B'' ; p3: A1'' ; p4: none. Reads: p1: B1(tau); p2: A1(tau);
// p4: A0,B0(tau+1). ONE wait per tile: vmcnt(7) at p3 -- outstanding there =
// tile(tau+1)'s 7 + tile(tau+2)'s 7 = 14; retire the 7 oldest => ALL of tile
// tau+1's data landed, covering p4's A0/B0 reads and next tile's p1/p2 reads.
__device__ __forceinline__ void stage_B192(char* ldsRegion, const bf16* gsrc) {
    const int t = threadIdx.x;
    const int wid = t >> 6;
#pragma unroll
    for (int i = 0; i < 3; ++i) {
        const int off = i * 8192 + t * 16;
        const int row = off >> 7;
        const int pc = (off >> 4) & 7;
        const int lc = pc ^ (row & 7);
        gload_lds16(gsrc + (size_t)row * 4096 + lc * 8,
                    ldsRegion + i * 8192 + wid * 1024);
    }
}

__device__ __forceinline__ void gemm192(const bf16* __restrict__ At,
                                        const bf16* __restrict__ Bt,
                                        char* LB, f32x4 acc[8][3]) {
    const int tid = threadIdx.x, lane = tid & 63, wid = tid >> 6;
    const int wm = wid >> 2, wn = wid & 3;
    const int l15 = lane & 15, l4 = lane >> 4;

    const f32x4 vz = {0.f, 0.f, 0.f, 0.f};
#pragma unroll
    for (int m = 0; m < 8; ++m)
#pragma unroll
        for (int n = 0; n < 3; ++n) acc[m][n] = vz;

    auto Areg = [&](int db, int h) -> char* { return LB + db * 32768 + h * 16384; };
    auto Breg = [&](int db) -> char* { return LB + 65536 + db * 24576; };

    bf16x8 RA[2][4], RAb[2][4], RB0[2][2], RB1[2];

    auto loadA = [&](bf16x8 dst[2][4], int db, int h) {
        char* base = Areg(db, h);
#pragma unroll
        for (int kk = 0; kk < 2; ++kk)
#pragma unroll
            for (int mf = 0; mf < 4; ++mf) {
                const int row = wm * 64 + mf * 16 + l15;
                const int cc = kk * 4 + l4;
                dst[kk][mf] = *(const bf16x8*)(base + row * 128 + ((cc ^ (row & 7)) << 4));
            }
    };
    auto loadB0 = [&](int db) {
        char* base = Breg(db);
#pragma unroll
        for (int kk = 0; kk < 2; ++kk)
#pragma unroll
            for (int nf = 0; nf < 2; ++nf) {
                const int row = wn * 48 + nf * 16 + l15;
                const int cc = kk * 4 + l4;
                RB0[kk][nf] = *(const bf16x8*)(base + row * 128 + ((cc ^ (row & 7)) << 4));
            }
    };
    auto loadB1 = [&](int db) {
        char* base = Breg(db);
#pragma unroll
        for (int kk = 0; kk < 2; ++kk) {
            const int row = wn * 48 + 32 + l15;
            const int cc = kk * 4 + l4;
            RB1[kk] = *(const bf16x8*)(base + row * 128 + ((cc ^ (row & 7)) << 4));
        }
    };
    auto stA = [&](int tau, int h) {
        stage_half(Areg(tau & 1, h), At + (size_t)(h * 128) * 4096 + tau * 64);
    };
    auto stB = [&](int tau) {
        stage_B192(Breg(tau & 1), Bt + tau * 64);
    };
    auto mmaB0 = [&](bf16x8 A[2][4], int mb) {   // 16 MFMA
        __builtin_amdgcn_s_setprio(1);
#pragma unroll
        for (int kk = 0; kk < 2; ++kk)
#pragma unroll
            for (int mf = 0; mf < 4; ++mf)
#pragma unroll
                for (int nf = 0; nf < 2; ++nf)
                    acc[mb + mf][nf] = MFMA16(A[kk][mf], RB0[kk][nf], acc[mb + mf][nf]);
        __builtin_amdgcn_s_setprio(0);
    };
    auto mmaB1 = [&](bf16x8 A[2][4], int mb) {   // 8 MFMA
        __builtin_amdgcn_s_setprio(1);
#pragma unroll
        for (int kk = 0; kk < 2; ++kk)
#pragma unroll
            for (int mf = 0; mf < 4; ++mf)
                acc[mb + mf][2] = MFMA16(A[kk][mf], RB1[kk], acc[mb + mf][2]);
        __builtin_amdgcn_s_setprio(0);
    };

    // prologue: stage tiles 0,1 (14 loads/thread); vmcnt(7) => tile0 landed
    stA(0, 0); stB(0); stA(0, 1);
    stA(1, 0); stB(1); stA(1, 1);
    VMW7();
    BAR();
    loadA(RA, 0, 0); loadB0(0);

#pragma unroll 1
    for (int tau = 0; tau < NTILES - 2; ++tau) {
        const int db = tau & 1, ndb = db ^ 1;
        // p1: read tau.B1 ; stage (tau+2).A0 ; MFMA (A0,B0)
        loadB1(db);
        stA(tau + 2, 0);
        BAR();
        mmaB0(RA, 0);
        BAR();
        // p2: read tau.A1 ; stage (tau+2).B ; MFMA (A0,B1)
        loadA(RAb, db, 1);
        stB(tau + 2);
        BAR();
        mmaB1(RA, 0);
        BAR();
        // p3: stage (tau+2).A1 ; vmcnt(7) ; MFMA (A1,B0)
        stA(tau + 2, 1);
        VMW7();
        BAR();
        mmaB0(RAb, 4);
        BAR();
        // p4: read (tau+1).{A0,B0} ; MFMA (A1,B1)
        loadA(RA, ndb, 0);
        loadB0(ndb);
        BAR();
        mmaB1(RAb, 4);
        BAR();
    }

    // tail: tiles 62,63 fully staged; one drain, then barrier-free compute
    asm volatile("s_waitcnt vmcnt(0)" ::: "memory");
    BAR();
#pragma unroll 1
    for (int tau = NTILES - 2; tau < NTILES; ++tau) {
        const int db = tau & 1, ndb = db ^ 1;
        loadB1(db);
        mmaB0(RA, 0);
        loadA(RAb, db, 1);
        mmaB1(RA, 0);
        mmaB0(RAb, 4);
        if (tau < NTILES - 1) { loadA(RA, ndb, 0); loadB0(ndb); }
        mmaB1(RAb, 4);
    }
}

// bijective XCD-chunk swizzle (nwg % 8 == 0 for all our grids)
__device__ __forceinline__ void xcd_swizzle(int gx, int& bx, int& by) {
    const int nwg = gx * gridDim.y;
    int lin = by * gx + bx;
    lin = (lin & 7) * (nwg >> 3) + (lin >> 3);
    bx = lin % gx;
    by = lin / gx;
}

// ---------------- GEMM 1: xqkv = x @ wqkv (256x192 tiles), fused RoPE ----------------
__global__ __launch_bounds__(512, 2) void k_gemm_qkv(const bf16* __restrict__ A,
                                                     const bf16* __restrict__ Bt,
                                                     const float* __restrict__ fc,
                                                     bf16* __restrict__ Qb,
                                                     bf16* __restrict__ Kb,
                                                     bf16* __restrict__ VTb) {
    __shared__ __align__(16) char LB[114688];
    f32x4 acc[8][3];
    int bx = blockIdx.x, by = blockIdx.y;
    xcd_swizzle(NQKV / 192, bx, by);
    gemm192(A + (size_t)by * 256 * 4096, Bt + (size_t)bx * 192 * 4096, LB, acc);

    const int tid = threadIdx.x, lane = tid & 63, wid = tid >> 6;
    const int wm = wid >> 2, wn = wid & 3;
    const int l15 = lane & 15, l4 = lane >> 4;
#pragma unroll
    for (int mf = 0; mf < 8; ++mf) {
        const int rowbase = by * 256 + (mf >> 2) * 128 + wm * 64 + (mf & 3) * 16 + l4 * 4;
#pragma unroll
        for (int nf = 0; nf < 3; ++nf) {
            const int rb = bx * 192 + wn * 48 + nf * 16;  // frag base, lane-uniform
            const int col = rb + l15;                     // Q/K/V bounds are 16-aligned
            f32x4 v = acc[mf][nf];
            if (rb < QDIM + KVDIM) {
                // Q or K: RoPE. Paired column col^1 lives in lane^1 (C-layout col=lane&15).
                const int d = col & (HD - 1);
                const int dp = d & ~1;
                const float sgn = (d & 1) ? 1.f : -1.f;
#pragma unroll
                for (int r = 0; r < 4; ++r) {
                    const int row = rowbase + r;
                    const int s = row & (SS - 1);
                    const float2 sc = *(const float2*)(fc + s * HD + dp);  // (sin, cos)
                    const float partner = __shfl_xor(v[r], 1);
                    float res = v[r] * sc.y + sgn * partner * sc.x;
                    if (rb < QDIM) {
                        res *= QK_SCALE_L2E;
                        Qb[(size_t)row * QDIM + col] = (bf16)res;
                    } else {
                        Kb[(size_t)row * KVDIM + (col - QDIM)] = (bf16)res;
                    }
                }
            } else {
                // V: write transposed [b][kvh][d][s]; 4 consecutive s -> 8B store
                const int hdv = col - (QDIM + KVDIM);
                const int kvh = hdv >> 7, dd = hdv & (HD - 1);
                const int bb = rowbase >> 11, s = rowbase & (SS - 1);
                bf16x4 pk;
#pragma unroll
                for (int r = 0; r < 4; ++r) pk[r] = (bf16)v[r];
                *(bf16x4*)(VTb + ((size_t)((bb * NKV + kvh) * HD + dd)) * SS + s) = pk;
            }
        }
    }
}

// ---------------- GEMM 2: out = attn @ wo (f32 output, 256x256 tiles) ----------------
__global__ __launch_bounds__(512, 2) void k_gemm_out(const bf16* __restrict__ A,
                                                     const bf16* __restrict__ Bt,
                                                     float* __restrict__ out) {
    __shared__ __align__(16) char LB[131072];
    f32x4 acc[8][4];
    int bx = blockIdx.x, by = blockIdx.y;
    xcd_swizzle(DD / 256, bx, by);
    gemm256(A + (size_t)by * 256 * 4096, Bt + (size_t)bx * 256 * 4096, LB, acc);

    const int tid = threadIdx.x, lane = tid & 63, wid = tid >> 6;
    const int wm = wid >> 2, wn = wid & 3;
    const int l15 = lane & 15, l4 = lane >> 4;
#pragma unroll
    for (int mf = 0; mf < 8; ++mf) {
        const int row = by * 256 + (mf >> 2) * 128 + wm * 64 + (mf & 3) * 16 + l4 * 4;
#pragma unroll
        for (int nf = 0; nf < 4; ++nf) {
            const int col = bx * 256 + (nf >> 1) * 128 + wn * 32 + (nf & 1) * 16 + l15;
#pragma unroll
            for (int r = 0; r < 4; ++r) out[(size_t)(row + r) * DD + col] = acc[mf][nf][r];
        }
    }
}

// ---------------- flash attention (r5 structure, unchanged) ----------------
__global__ __launch_bounds__(256, 2) void k_attn(const bf16* __restrict__ Qb,
                                                 const bf16* __restrict__ Kb,
                                                 const bf16* __restrict__ VTb,
                                                 bf16* __restrict__ Ob) {
    __shared__ __align__(16) bf16 Ks[64 * 128];
    __shared__ __align__(16) bf16 Vs[128 * 64];
    __shared__ __align__(16) bf16 Ps[4][32 * 88];
    // swizzle 512 blocks -> 64 consecutive per XCD (2 kvh-groups' K/V L2-resident)
    int lin = (blockIdx.z * NH + blockIdx.y) * 8 + blockIdx.x;
    lin = (lin & 7) * 64 + (lin >> 3);
    const int jj = lin & 7, h = (lin >> 3) & (NH - 1), b = lin >> 8;
    const int kvh = h >> 2;
    const int tid = threadIdx.x, lane = tid & 63, w = tid >> 6;
    const int l15 = lane & 15, l4 = lane >> 4;

    const bf16* Kg = Kb + (size_t)b * SS * KVDIM + kvh * HD;
    const bf16* Vg = VTb + (size_t)(b * NKV + kvh) * HD * SS;

    int4 kreg[4], vreg[4];
    const f32x4 vz = {0.f, 0.f, 0.f, 0.f};

    auto issue_kv = [&](int t) {
#pragma unroll
        for (int i = 0; i < 4; ++i) {
            const int off = i * 4096 + tid * 16;
            const int row = off >> 8;
            const int cc = (off >> 4) & 15;
            kreg[i] = *(const int4*)((const char*)(Kg + (size_t)(t * 64 + row) * KVDIM) + cc * 16);
        }
#pragma unroll
        for (int i = 0; i < 4; ++i) {
            const int off = i * 4096 + tid * 16;
            const int row = off >> 7;
            const int cc = (off >> 4) & 7;
            vreg[i] = *(const int4*)((const char*)(Vg + (size_t)row * SS + t * 64) + cc * 16);
        }
    };

#pragma unroll 1
    for (int pj = 0; pj < 2; ++pj) {
        const int j = pj ? (15 - jj) : jj;
        const int q0 = j * 128;
        const int nt = 2 * j + 2;

        bf16x8 qf[2][4];
#pragma unroll
        for (int m = 0; m < 2; ++m) {
            const int qrow = q0 + w * 32 + m * 16 + l15;
            const bf16* qb = Qb + ((size_t)(b * SS + qrow) << 12) + h * HD + l4 * 8;
#pragma unroll
            for (int kc = 0; kc < 4; ++kc) qf[m][kc] = *(const bf16x8*)(qb + kc * 32);
        }

        f32x4 o[2][8];
#pragma unroll
        for (int m = 0; m < 2; ++m)
#pragma unroll
            for (int df = 0; df < 8; ++df) o[m][df] = vz;
        float m_run[2][4], l_run[2][4];
#pragma unroll
        for (int m = 0; m < 2; ++m)
#pragma unroll
            for (int r = 0; r < 4; ++r) { m_run[m][r] = -1e30f; l_run[m][r] = 0.f; }

        issue_kv(0);

        for (int t = 0; t < nt; ++t) {
            __syncthreads();
#pragma unroll
            for (int i = 0; i < 4; ++i) {
                const int off = i * 4096 + tid * 16;
                const int row = off >> 8;
                const int cc = (off >> 4) & 15;
                const int lc = cc ^ (row & 7);
                *(int4*)((char*)Ks + row * 256 + lc * 16) = kreg[i];
            }
#pragma unroll
            for (int i = 0; i < 4; ++i) {
                const int off = i * 4096 + tid * 16;
                const int row = off >> 7;
                const int cc = (off >> 4) & 7;
                const int lc = cc ^ (row & 7);
                *(int4*)((char*)Vs + row * 128 + lc * 16) = vreg[i];
            }
            __syncthreads();

            if (t + 1 < nt) issue_kv(t + 1);

            f32x4 sa[2][4];
#pragma unroll
            for (int m = 0; m < 2; ++m)
#pragma unroll
                for (int n = 0; n < 4; ++n) sa[m][n] = vz;
            __builtin_amdgcn_s_setprio(1);
#pragma unroll
            for (int kc = 0; kc < 4; ++kc)
#pragma unroll
                for (int n = 0; n < 4; ++n) {
                    const int krow = n * 16 + l15;
                    const int cc = kc * 4 + l4;
                    const bf16x8 kf =
                        *(const bf16x8*)((const char*)Ks + (krow << 8) + ((cc ^ (krow & 7)) << 4));
                    sa[0][n] = MFMA16(qf[0][kc], kf, sa[0][n]);
                    sa[1][n] = MFMA16(qf[1][kc], kf, sa[1][n]);
                }
            __builtin_amdgcn_s_setprio(0);

            if (t >= 2 * j) {
#pragma unroll
                for (int m = 0; m < 2; ++m)
#pragma unroll
                    for (int n = 0; n < 4; ++n)
#pragma unroll
                        for (int r = 0; r < 4; ++r) {
                            const int col = t * 64 + n * 16 + l15;
                            const int qr = q0 + w * 32 + m * 16 + l4 * 4 + r;
                            if (col > qr) sa[m][n][r] = -1e30f;
                        }
            }

#pragma unroll
            for (int m = 0; m < 2; ++m)
#pragma unroll
                for (int r = 0; r < 4; ++r) {
                    float mx = fmaxf(fmaxf(sa[m][0][r], sa[m][1][r]),
                                     fmaxf(sa[m][2][r], sa[m][3][r]));
#pragma unroll
                    for (int mk = 1; mk <= 8; mk <<= 1) mx = fmaxf(mx, __shfl_xor(mx, mk));
                    const float mn = fmaxf(m_run[m][r], mx);
                    const float alpha = fexp2(m_run[m][r] - mn);
                    m_run[m][r] = mn;
                    float rs = 0.f;
#pragma unroll
                    for (int n = 0; n < 4; ++n) {
                        const float p = fexp2(sa[m][n][r] - mn);
                        sa[m][n][r] = p;
                        rs += p;
                    }
#pragma unroll
                    for (int mk = 1; mk <= 8; mk <<= 1) rs += __shfl_xor(rs, mk);
                    l_run[m][r] = l_run[m][r] * alpha + rs;
#pragma unroll
                    for (int df = 0; df < 8; ++df) o[m][df][r] *= alpha;
                }

#pragma unroll
            for (int m = 0; m < 2; ++m)
#pragma unroll
                for (int n = 0; n < 4; ++n)
#pragma unroll
                    for (int r = 0; r < 4; ++r)
                        Ps[w][(m * 16 + l4 * 4 + r) * 88 + n * 16 + l15] = (bf16)sa[m][n][r];

            bf16x8 pf0[2], pf1[2];
#pragma unroll
            for (int ks = 0; ks < 2; ++ks) {
                pf0[ks] = *(const bf16x8*)(&Ps[w][l15 * 88 + ks * 32 + l4 * 8]);
                pf1[ks] = *(const bf16x8*)(&Ps[w][(16 + l15) * 88 + ks * 32 + l4 * 8]);
            }

            __builtin_amdgcn_s_setprio(1);
#pragma unroll
            for (int df = 0; df < 8; ++df)
#pragma unroll
                for (int ks = 0; ks < 2; ++ks) {
                    const int vrow = df * 16 + l15;
                    const int cc = ks * 4 + l4;
                    const bf16x8 vf =
                        *(const bf16x8*)((const char*)Vs + (vrow << 7) + ((cc ^ (vrow & 7)) << 4));
                    o[0][df] = MFMA16(pf0[ks], vf, o[0][df]);
                    o[1][df] = MFMA16(pf1[ks], vf, o[1][df]);
                }
            __builtin_amdgcn_s_setprio(0);
        }

#pragma unroll
        for (int m = 0; m < 2; ++m)
#pragma unroll
            for (int r = 0; r < 4; ++r) {
                const float inv = 1.f / l_run[m][r];
                const size_t row = (size_t)(b * SS + q0 + w * 32 + m * 16 + l4 * 4 + r);
#pragma unroll
                for (int df = 0; df < 8; ++df)
                    Ob[(row << 12) + h * HD + df * 16 + l15] = (bf16)(o[m][df][r] * inv);
            }
    }
}

// ---------------- launcher ----------------
extern "C" void kernel_launch(void* const* d_in, const int* in_sizes, int n_in,
                              void* d_out, int out_size, void* d_ws, size_t ws_size,
                              hipStream_t stream) {
    const float* x    = (const float*)d_in[0];
    const float* fc   = (const float*)d_in[1];
    const float* wqkv = (const float*)d_in[2];
    const float* wo   = (const float*)d_in[3];

    char* wsp = (char*)d_ws;
    const size_t MB = (size_t)1 << 20;
    bf16* xb    = (bf16*)(wsp);              // 32MB
    bf16* wqkvT = (bf16*)(wsp + 32 * MB);    // 48MB
    bf16* woT   = (bf16*)(wsp + 32 * MB);    // 32MB (aliases wqkvT; written after gemm_qkv)
    bf16* Qb    = (bf16*)(wsp + 80 * MB);    // 32MB
    bf16* Kb    = (bf16*)(wsp + 112 * MB);   //  8MB
    bf16* VTb   = (bf16*)(wsp + 120 * MB);   //  8MB
    bf16* Ab    = (bf16*)(wsp);              // attn out bf16 (aliases xb)
    float* out  = (float*)d_out;

    k_cvt_x<<<8192, 256, 0, stream>>>(x, xb);
    k_tr_cvt<<<dim3(NQKV / 64, DD / 64), 256, 0, stream>>>(wqkv, wqkvT, DD, NQKV);
    k_gemm_qkv<<<dim3(NQKV / 192, (BB * SS) / 256), 512, 0, stream>>>(xb, wqkvT, fc, Qb, Kb, VTb);
    k_tr_cvt<<<dim3(DD / 64, QDIM / 64), 256, 0, stream>>>(wo, woT, QDIM, DD);
    k_attn<<<dim3(8, NH, BB), 256, 0, stream>>>(Qb, Kb, VTb, Ab);
    k_gemm_out<<<dim3(DD / 256, (BB * SS) / 256), 512, 0, stream>>>(Ab, woT, out);
}

// Round 9
// 569.461 us; speedup vs baseline: 7.5546x; 1.0028x over previous
//
#include <hip/hip_runtime.h>
#include <stdint.h>
#include <stddef.h>

// ---------------- problem constants ----------------
#define BB 2
#define SS 2048
#define DD 4096
#define NH 32
#define NKV 8
#define HD 128
#define QDIM 4096
#define KVDIM 1024
#define NQKV 6144
#define NTILES 64  // K / 64
// 1/sqrt(128) * log2(e): Q pre-scale so softmax exp is a single v_exp_f32 (2^x)
#define QK_SCALE_L2E 0.12751744f

typedef __bf16 bf16;
typedef __bf16 bf16x8 __attribute__((ext_vector_type(8)));
typedef __bf16 bf16x4 __attribute__((ext_vector_type(4)));
typedef float f32x4 __attribute__((ext_vector_type(4)));

#define MFMA16(a, b, c) __builtin_amdgcn_mfma_f32_16x16x32_bf16((a), (b), (c), 0, 0, 0)
#define VMW5() asm volatile("s_waitcnt vmcnt(5)" ::: "memory")
#define VMW4() asm volatile("s_waitcnt vmcnt(4)" ::: "memory")
#define VMW2() asm volatile("s_waitcnt vmcnt(2)" ::: "memory")
#define VMW0() asm volatile("s_waitcnt vmcnt(0)" ::: "memory")
// Barrier that is also a hard compile-time scheduling fence: raw s_barrier is
// IntrNoMem in LLVM, so loads/stages can migrate across it (the r8 race).
#define BARX()                                  \
    do {                                        \
        __builtin_amdgcn_s_barrier();           \
        __builtin_amdgcn_sched_barrier(0);      \
    } while (0)
// rule #18: explicit lgkmcnt(0) must be followed by sched_barrier(0)
#define LGKM0_SGB()                                         \
    do {                                                    \
        asm volatile("s_waitcnt lgkmcnt(0)" ::: "memory");  \
        __builtin_amdgcn_sched_barrier(0);                  \
    } while (0)

typedef __attribute__((address_space(1))) void GASV;
typedef __attribute__((address_space(3))) void LASV;

__device__ __forceinline__ void gload_lds16(const void* g, void* l) {
    __builtin_amdgcn_global_load_lds((GASV*)g, (LASV*)l, 16, 0, 0);
}

__device__ __forceinline__ float fexp2(float x) {
    float r;
    asm("v_exp_f32 %0, %1" : "=v"(r) : "v"(x));
    return r;
}

// ---------------- fp32 -> bf16 convert (x) ----------------
__global__ __launch_bounds__(256) void k_cvt_x(const float* __restrict__ in,
                                               bf16* __restrict__ out) {
    size_t i = ((size_t)blockIdx.x * 256 + threadIdx.x) * 8;
    const float4 a = *(const float4*)(in + i);
    const float4 b = *(const float4*)(in + i + 4);
    bf16x8 v;
    v[0] = (bf16)a.x; v[1] = (bf16)a.y; v[2] = (bf16)a.z; v[3] = (bf16)a.w;
    v[4] = (bf16)b.x; v[5] = (bf16)b.y; v[6] = (bf16)b.z; v[7] = (bf16)b.w;
    *(bf16x8*)(out + i) = v;
}

// ---------------- transpose + convert: in[R][C] f32 -> out[C][R] bf16 ----------------
__global__ __launch_bounds__(256) void k_tr_cvt(const float* __restrict__ in,
                                                bf16* __restrict__ out, int R, int C) {
    __shared__ float tile[64][65];
    const int t = threadIdx.x;
    const int tx = t & 15, ty = t >> 4;
    const int r0 = blockIdx.y * 64, c0 = blockIdx.x * 64;
#pragma unroll
    for (int p = 0; p < 4; ++p) {
        const float4 v = *(const float4*)(in + (size_t)(r0 + p * 16 + ty) * C + c0 + tx * 4);
        tile[p * 16 + ty][tx * 4 + 0] = v.x;
        tile[p * 16 + ty][tx * 4 + 1] = v.y;
        tile[p * 16 + ty][tx * 4 + 2] = v.z;
        tile[p * 16 + ty][tx * 4 + 3] = v.w;
    }
    __syncthreads();
#pragma unroll
    for (int p = 0; p < 4; ++p) {
        const int oc = c0 + p * 16 + ty;
        bf16x4 pk;
#pragma unroll
        for (int j = 0; j < 4; ++j) pk[j] = (bf16)tile[tx * 4 + j][p * 16 + ty];
        *(bf16x4*)(out + (size_t)oc * R + r0 + tx * 4) = pk;
    }
}

// ---- shared staging helper: 128-row x 64-k half (16KB), 2 loads/thread ----
__device__ __forceinline__ void stage_half(char* ldsRegion, const bf16* gsrc) {
    const int t = threadIdx.x;
    const int wid = t >> 6;
#pragma unroll
    for (int i = 0; i < 2; ++i) {
        const int off = i * 8192 + t * 16;
        const int row = off >> 7;          // 128B rows
        const int pc = (off >> 4) & 7;     // phys chunk
        const int lc = pc ^ (row & 7);     // logical chunk fetched into phys slot
        gload_lds16(gsrc + (size_t)row * 4096 + lc * 8,
                    ldsRegion + i * 8192 + wid * 1024);
    }
}

// ================= 256x256 core (r9: depth-1 dbuf, 3 phases, counted vmcnt) ========
// 8 waves (2M x 4N). Tile tau stages tile tau+1 into buffer ndb (NOT the buffer
// being read) -- overwrite of tile tau-1's region is issued >= 2 full phases after
// its last read. Per tile (4 stages x 2 loads = 8):
//   P1: read A0,B0(tau); stage {A0,B0}(tau+1); VMW4; BARX; LGKM0; 16 MFMA; BARX
//   P2: read B1(tau);    stage {B1,A1}(tau+1);       BARX; LGKM0; 16 MFMA; BARX
//   P3: read A1(tau);                          VMW4; BARX; LGKM0; 32 MFMA; BARX
// FIFO: at P1's VMW4, outstanding = {B1A1(tau)(4), A0B0(tau+1)(4)} -> retires
// B1A1(tau) (covers P2/P3 reads). At P3's VMW4, outstanding = {A0B0(tau+1)(4),
// B1A1(tau+1)(4)} -> retires A0B0(tau+1) (covers tau+1.P1 reads). Every load is
// waited exactly 2 phases after issue. Every read's guarantee VMW+BAR precedes
// its earliest legal hoist position (LGKM0_SGB of the prior phase).
__device__ __forceinline__ void gemm256(const bf16* __restrict__ At,
                                        const bf16* __restrict__ Bt,
                                        char* LB, f32x4 acc[8][4]) {
    const int tid = threadIdx.x, lane = tid & 63, wid = tid >> 6;
    const int wm = wid >> 2, wn = wid & 3;
    const int l15 = lane & 15, l4 = lane >> 4;

    const f32x4 vz = {0.f, 0.f, 0.f, 0.f};
#pragma unroll
    for (int m = 0; m < 8; ++m)
#pragma unroll
        for (int n = 0; n < 4; ++n) acc[m][n] = vz;

    auto Areg = [&](int db, int h) -> char* { return LB + db * 32768 + h * 16384; };
    auto Breg = [&](int db, int h) -> char* { return LB + 65536 + db * 32768 + h * 16384; };

    bf16x8 RA[2][4], RAb[2][4], RB0[2][2], RB1[2][2];

    auto loadA = [&](bf16x8 dst[2][4], int db, int h) {
        char* base = Areg(db, h);
#pragma unroll
        for (int kk = 0; kk < 2; ++kk)
#pragma unroll
            for (int mf = 0; mf < 4; ++mf) {
                const int row = wm * 64 + mf * 16 + l15;
                const int cc = kk * 4 + l4;
                dst[kk][mf] = *(const bf16x8*)(base + row * 128 + ((cc ^ (row & 7)) << 4));
            }
    };
    auto loadB = [&](bf16x8 dst[2][2], int db, int h) {
        char* base = Breg(db, h);
#pragma unroll
        for (int kk = 0; kk < 2; ++kk)
#pragma unroll
            for (int nf = 0; nf < 2; ++nf) {
                const int row = wn * 32 + nf * 16 + l15;
                const int cc = kk * 4 + l4;
                dst[kk][nf] = *(const bf16x8*)(base + row * 128 + ((cc ^ (row & 7)) << 4));
            }
    };
    auto stA = [&](int tau, int h) {
        stage_half(Areg(tau & 1, h), At + (size_t)(h * 128) * 4096 + tau * 64);
    };
    auto stB = [&](int tau, int h) {
        stage_half(Breg(tau & 1, h), Bt + (size_t)(h * 128) * 4096 + tau * 64);
    };
    auto mma = [&](bf16x8 A[2][4], bf16x8 B[2][2], int mb, int nb) {
        __builtin_amdgcn_s_setprio(1);
#pragma unroll
        for (int kk = 0; kk < 2; ++kk)
#pragma unroll
            for (int mf = 0; mf < 4; ++mf)
#pragma unroll
                for (int nf = 0; nf < 2; ++nf)
                    acc[mb + mf][nb + nf] = MFMA16(A[kk][mf], B[kk][nf], acc[mb + mf][nb + nf]);
        __builtin_amdgcn_s_setprio(0);
    };

    // ---- prologue: stage tile 0 ({A0,B0} then {B1,A1}); retire A0B0(0)
    stA(0, 0); stB(0, 0);
    stB(0, 1); stA(0, 1);
    VMW4();
    BARX();

    // ---- main loop: tiles 0..62, staging tiles 1..63
#pragma unroll 1
    for (int tau = 0; tau < NTILES - 1; ++tau) {
        const int db = tau & 1;
        // P1
        loadA(RA, db, 0);
        loadB(RB0, db, 0);
        stA(tau + 1, 0);
        stB(tau + 1, 0);
        VMW4();
        BARX(); LGKM0_SGB();
        mma(RA, RB0, 0, 0);
        BARX();
        // P2
        loadB(RB1, db, 1);
        stB(tau + 1, 1);
        stA(tau + 1, 1);
        BARX(); LGKM0_SGB();
        mma(RA, RB1, 0, 2);
        BARX();
        // P3
        loadA(RAb, db, 1);
        VMW4();
        BARX(); LGKM0_SGB();
        mma(RAb, RB0, 4, 0);
        mma(RAb, RB1, 4, 2);
        BARX();
    }

    // ---- tail: tile 63 fully staged; one drain, no further stages
    VMW0();
    BARX();
    {
        const int db = (NTILES - 1) & 1;
        loadA(RA, db, 0);
        loadB(RB0, db, 0);
        mma(RA, RB0, 0, 0);
        loadB(RB1, db, 1);
        mma(RA, RB1, 0, 2);
        loadA(RAb, db, 1);
        mma(RAb, RB0, 4, 0);
        mma(RAb, RB1, 4, 2);
    }
}

// ================= 256x192 core (r9: depth-1 dbuf, 3 phases, counted vmcnt) ========
// Per-wave C = 128 rows x 48 cols (3 n-frags split 2+1). Per tile (7 loads):
//   P1: read A0,B0(tau); stage {A0,B}(tau+1) (5); VMW5; BARX; LGKM0; 16 MFMA; BARX
//   P2: read B1(tau);    stage {A1}(tau+1) (2);         BARX; LGKM0;  8 MFMA; BARX
//   P3: read A1(tau);                            VMW2; BARX; LGKM0; 24 MFMA; BARX
// FIFO: at P1's VMW5, outstanding = {A1(tau)(2), A0B(tau+1)(5)} -> retires A1(tau).
// At P3's VMW2, outstanding = {A0B(tau+1)(5), A1(tau+1)(2)} -> retires A0B(tau+1).
__device__ __forceinline__ void stage_B192(char* ldsRegion, const bf16* gsrc) {
    const int t = threadIdx.x;
    const int wid = t >> 6;
#pragma unroll
    for (int i = 0; i < 3; ++i) {
        const int off = i * 8192 + t * 16;
        const int row = off >> 7;
        const int pc = (off >> 4) & 7;
        const int lc = pc ^ (row & 7);
        gload_lds16(gsrc + (size_t)row * 4096 + lc * 8,
                    ldsRegion + i * 8192 + wid * 1024);
    }
}

__device__ __forceinline__ void gemm192(const bf16* __restrict__ At,
                                        const bf16* __restrict__ Bt,
                                        char* LB, f32x4 acc[8][3]) {
    const int tid = threadIdx.x, lane = tid & 63, wid = tid >> 6;
    const int wm = wid >> 2, wn = wid & 3;
    const int l15 = lane & 15, l4 = lane >> 4;

    const f32x4 vz = {0.f, 0.f, 0.f, 0.f};
#pragma unroll
    for (int m = 0; m < 8; ++m)
#pragma unroll
        for (int n = 0; n < 3; ++n) acc[m][n] = vz;

    auto Areg = [&](int db, int h) -> char* { return LB + db * 32768 + h * 16384; };
    auto Breg = [&](int db) -> char* { return LB + 65536 + db * 24576; };

    bf16x8 RA[2][4], RAb[2][4], RB0[2][2], RB1[2];

    auto loadA = [&](bf16x8 dst[2][4], int db, int h) {
        char* base = Areg(db, h);
#pragma unroll
        for (int kk = 0; kk < 2; ++kk)
#pragma unroll
            for (int mf = 0; mf < 4; ++mf) {
                const int row = wm * 64 + mf * 16 + l15;
                const int cc = kk * 4 + l4;
                dst[kk][mf] = *(const bf16x8*)(base + row * 128 + ((cc ^ (row & 7)) << 4));
            }
    };
    auto loadB0 = [&](int db) {
        char* base = Breg(db);
#pragma unroll
        for (int kk = 0; kk < 2; ++kk)
#pragma unroll
            for (int nf = 0; nf < 2; ++nf) {
                const int row = wn * 48 + nf * 16 + l15;
                const int cc = kk * 4 + l4;
                RB0[kk][nf] = *(const bf16x8*)(base + row * 128 + ((cc ^ (row & 7)) << 4));
            }
    };
    auto loadB1 = [&](int db) {
        char* base = Breg(db);
#pragma unroll
        for (int kk = 0; kk < 2; ++kk) {
            const int row = wn * 48 + 32 + l15;
            const int cc = kk * 4 + l4;
            RB1[kk] = *(const bf16x8*)(base + row * 128 + ((cc ^ (row & 7)) << 4));
        }
    };
    auto stA = [&](int tau, int h) {
        stage_half(Areg(tau & 1, h), At + (size_t)(h * 128) * 4096 + tau * 64);
    };
    auto stB = [&](int tau) {
        stage_B192(Breg(tau & 1), Bt + tau * 64);
    };
    auto mmaB0 = [&](bf16x8 A[2][4], int mb) {   // 16 MFMA
        __builtin_amdgcn_s_setprio(1);
#pragma unroll
        for (int kk = 0; kk < 2; ++kk)
#pragma unroll
            for (int mf = 0; mf < 4; ++mf)
#pragma unroll
                for (int nf = 0; nf < 2; ++nf)
                    acc[mb + mf][nf] = MFMA16(A[kk][mf], RB0[kk][nf], acc[mb + mf][nf]);
        __builtin_amdgcn_s_setprio(0);
    };
    auto mmaB1 = [&](bf16x8 A[2][4], int mb) {   // 8 MFMA
        __builtin_amdgcn_s_setprio(1);
#pragma unroll
        for (int kk = 0; kk < 2; ++kk)
#pragma unroll
            for (int mf = 0; mf < 4; ++mf)
                acc[mb + mf][2] = MFMA16(A[kk][mf], RB1[kk], acc[mb + mf][2]);
        __builtin_amdgcn_s_setprio(0);
    };

    // ---- prologue: stage tile 0 ({A0,B} then {A1}); retire A0B(0)
    stA(0, 0); stB(0);
    stA(0, 1);
    VMW2();
    BARX();

    // ---- main loop: tiles 0..62, staging tiles 1..63
#pragma unroll 1
    for (int tau = 0; tau < NTILES - 1; ++tau) {
        const int db = tau & 1;
        // P1
        loadA(RA, db, 0);
        loadB0(db);
        stA(tau + 1, 0);
        stB(tau + 1);
        VMW5();
        BARX(); LGKM0_SGB();
        mmaB0(RA, 0);
        BARX();
        // P2
        loadB1(db);
        stA(tau + 1, 1);
        BARX(); LGKM0_SGB();
        mmaB1(RA, 0);
        BARX();
        // P3
        loadA(RAb, db, 1);
        VMW2();
        BARX(); LGKM0_SGB();
        mmaB0(RAb, 4);
        mmaB1(RAb, 4);
        BARX();
    }

    // ---- tail: tile 63 fully staged; one drain, no further stages
    VMW0();
    BARX();
    {
        const int db = (NTILES - 1) & 1;
        loadA(RA, db, 0);
        loadB0(db);
        mmaB0(RA, 0);
        loadB1(db);
        mmaB1(RA, 0);
        loadA(RAb, db, 1);
        mmaB0(RAb, 4);
        mmaB1(RAb, 4);
    }
}

// bijective XCD-chunk swizzle (nwg % 8 == 0 for all our grids)
__device__ __forceinline__ void xcd_swizzle(int gx, int& bx, int& by) {
    const int nwg = gx * gridDim.y;
    int lin = by * gx + bx;
    lin = (lin & 7) * (nwg >> 3) + (lin >> 3);
    bx = lin % gx;
    by = lin / gx;
}

// ---------------- GEMM 1: xqkv = x @ wqkv (256x192 tiles), fused RoPE ----------------
__global__ __launch_bounds__(512, 2) void k_gemm_qkv(const bf16* __restrict__ A,
                                                     const bf16* __restrict__ Bt,
                                                     const float* __restrict__ fc,
                                                     bf16* __restrict__ Qb,
                                                     bf16* __restrict__ Kb,
                                                     bf16* __restrict__ VTb) {
    __shared__ __align__(16) char LB[114688];
    f32x4 acc[8][3];
    int bx = blockIdx.x, by = blockIdx.y;
    xcd_swizzle(NQKV / 192, bx, by);
    gemm192(A + (size_t)by * 256 * 4096, Bt + (size_t)bx * 192 * 4096, LB, acc);

    const int tid = threadIdx.x, lane = tid & 63, wid = tid >> 6;
    const int wm = wid >> 2, wn = wid & 3;
    const int l15 = lane & 15, l4 = lane >> 4;
#pragma unroll
    for (int mf = 0; mf < 8; ++mf) {
        const int rowbase = by * 256 + (mf >> 2) * 128 + wm * 64 + (mf & 3) * 16 + l4 * 4;
#pragma unroll
        for (int nf = 0; nf < 3; ++nf) {
            const int rb = bx * 192 + wn * 48 + nf * 16;  // frag base, lane-uniform
            const int col = rb + l15;                     // Q/K/V bounds are 16-aligned
            f32x4 v = acc[mf][nf];
            if (rb < QDIM + KVDIM) {
                // Q or K: RoPE. Paired column col^1 lives in lane^1 (C-layout col=lane&15).
                const int d = col & (HD - 1);
                const int dp = d & ~1;
                const float sgn = (d & 1) ? 1.f : -1.f;
#pragma unroll
                for (int r = 0; r < 4; ++r) {
                    const int row = rowbase + r;
                    const int s = row & (SS - 1);
                    const float2 sc = *(const float2*)(fc + s * HD + dp);  // (sin, cos)
                    const float partner = __shfl_xor(v[r], 1);
                    float res = v[r] * sc.y + sgn * partner * sc.x;
                    if (rb < QDIM) {
                        res *= QK_SCALE_L2E;
                        Qb[(size_t)row * QDIM + col] = (bf16)res;
                    } else {
                        Kb[(size_t)row * KVDIM + (col - QDIM)] = (bf16)res;
                    }
                }
            } else {
                // V: write transposed [b][kvh][d][s]; 4 consecutive s -> 8B store
                const int hdv = col - (QDIM + KVDIM);
                const int kvh = hdv >> 7, dd = hdv & (HD - 1);
                const int bb = rowbase >> 11, s = rowbase & (SS - 1);
                bf16x4 pk;
#pragma unroll
                for (int r = 0; r < 4; ++r) pk[r] = (bf16)v[r];
                *(bf16x4*)(VTb + ((size_t)((bb * NKV + kvh) * HD + dd)) * SS + s) = pk;
            }
        }
    }
}

// ---------------- GEMM 2: out = attn @ wo (f32 output, 256x256 tiles) ----------------
__global__ __launch_bounds__(512, 2) void k_gemm_out(const bf16* __restrict__ A,
                                                     const bf16* __restrict__ Bt,
                                                     float* __restrict__ out) {
    __shared__ __align__(16) char LB[131072];
    f32x4 acc[8][4];
    int bx = blockIdx.x, by = blockIdx.y;
    xcd_swizzle(DD / 256, bx, by);
    gemm256(A + (size_t)by * 256 * 4096, Bt + (size_t)bx * 256 * 4096, LB, acc);

    const int tid = threadIdx.x, lane = tid & 63, wid = tid >> 6;
    const int wm = wid >> 2, wn = wid & 3;
    const int l15 = lane & 15, l4 = lane >> 4;
#pragma unroll
    for (int mf = 0; mf < 8; ++mf) {
        const int row = by * 256 + (mf >> 2) * 128 + wm * 64 + (mf & 3) * 16 + l4 * 4;
#pragma unroll
        for (int nf = 0; nf < 4; ++nf) {
            const int col = bx * 256 + (nf >> 1) * 128 + wn * 32 + (nf & 1) * 16 + l15;
#pragma unroll
            for (int r = 0; r < 4; ++r) out[(size_t)(row + r) * DD + col] = acc[mf][nf][r];
        }
    }
}

// ---------------- flash attention (r5 structure, unchanged) ----------------
__global__ __launch_bounds__(256, 2) void k_attn(const bf16* __restrict__ Qb,
                                                 const bf16* __restrict__ Kb,
                                                 const bf16* __restrict__ VTb,
                                                 bf16* __restrict__ Ob) {
    __shared__ __align__(16) bf16 Ks[64 * 128];
    __shared__ __align__(16) bf16 Vs[128 * 64];
    __shared__ __align__(16) bf16 Ps[4][32 * 88];
    // swizzle 512 blocks -> 64 consecutive per XCD (2 kvh-groups' K/V L2-resident)
    int lin = (blockIdx.z * NH + blockIdx.y) * 8 + blockIdx.x;
    lin = (lin & 7) * 64 + (lin >> 3);
    const int jj = lin & 7, h = (lin >> 3) & (NH - 1), b = lin >> 8;
    const int kvh = h >> 2;
    const int tid = threadIdx.x, lane = tid & 63, w = tid >> 6;
    const int l15 = lane & 15, l4 = lane >> 4;

    const bf16* Kg = Kb + (size_t)b * SS * KVDIM + kvh * HD;
    const bf16* Vg = VTb + (size_t)(b * NKV + kvh) * HD * SS;

    int4 kreg[4], vreg[4];
    const f32x4 vz = {0.f, 0.f, 0.f, 0.f};

    auto issue_kv = [&](int t) {
#pragma unroll
        for (int i = 0; i < 4; ++i) {
            const int off = i * 4096 + tid * 16;
            const int row = off >> 8;
            const int cc = (off >> 4) & 15;
            kreg[i] = *(const int4*)((const char*)(Kg + (size_t)(t * 64 + row) * KVDIM) + cc * 16);
        }
#pragma unroll
        for (int i = 0; i < 4; ++i) {
            const int off = i * 4096 + tid * 16;
            const int row = off >> 7;
            const int cc = (off >> 4) & 7;
            vreg[i] = *(const int4*)((const char*)(Vg + (size_t)row * SS + t * 64) + cc * 16);
        }
    };

#pragma unroll 1
    for (int pj = 0; pj < 2; ++pj) {
        const int j = pj ? (15 - jj) : jj;
        const int q0 = j * 128;
        const int nt = 2 * j + 2;

        bf16x8 qf[2][4];
#pragma unroll
        for (int m = 0; m < 2; ++m) {
            const int qrow = q0 + w * 32 + m * 16 + l15;
            const bf16* qb = Qb + ((size_t)(b * SS + qrow) << 12) + h * HD + l4 * 8;
#pragma unroll
            for (int kc = 0; kc < 4; ++kc) qf[m][kc] = *(const bf16x8*)(qb + kc * 32);
        }

        f32x4 o[2][8];
#pragma unroll
        for (int m = 0; m < 2; ++m)
#pragma unroll
            for (int df = 0; df < 8; ++df) o[m][df] = vz;
        float m_run[2][4], l_run[2][4];
#pragma unroll
        for (int m = 0; m < 2; ++m)
#pragma unroll
            for (int r = 0; r < 4; ++r) { m_run[m][r] = -1e30f; l_run[m][r] = 0.f; }

        issue_kv(0);

        for (int t = 0; t < nt; ++t) {
            __syncthreads();
#pragma unroll
            for (int i = 0; i < 4; ++i) {
                const int off = i * 4096 + tid * 16;
                const int row = off >> 8;
                const int cc = (off >> 4) & 15;
                const int lc = cc ^ (row & 7);
                *(int4*)((char*)Ks + row * 256 + lc * 16) = kreg[i];
            }
#pragma unroll
            for (int i = 0; i < 4; ++i) {
                const int off = i * 4096 + tid * 16;
                const int row = off >> 7;
                const int cc = (off >> 4) & 7;
                const int lc = cc ^ (row & 7);
                *(int4*)((char*)Vs + row * 128 + lc * 16) = vreg[i];
            }
            __syncthreads();

            if (t + 1 < nt) issue_kv(t + 1);

            f32x4 sa[2][4];
#pragma unroll
            for (int m = 0; m < 2; ++m)
#pragma unroll
                for (int n = 0; n < 4; ++n) sa[m][n] = vz;
            __builtin_amdgcn_s_setprio(1);
#pragma unroll
            for (int kc = 0; kc < 4; ++kc)
#pragma unroll
                for (int n = 0; n < 4; ++n) {
                    const int krow = n * 16 + l15;
                    const int cc = kc * 4 + l4;
                    const bf16x8 kf =
                        *(const bf16x8*)((const char*)Ks + (krow << 8) + ((cc ^ (krow & 7)) << 4));
                    sa[0][n] = MFMA16(qf[0][kc], kf, sa[0][n]);
                    sa[1][n] = MFMA16(qf[1][kc], kf, sa[1][n]);
                }
            __builtin_amdgcn_s_setprio(0);

            if (t >= 2 * j) {
#pragma unroll
                for (int m = 0; m < 2; ++m)
#pragma unroll
                    for (int n = 0; n < 4; ++n)
#pragma unroll
                        for (int r = 0; r < 4; ++r) {
                            const int col = t * 64 + n * 16 + l15;
                            const int qr = q0 + w * 32 + m * 16 + l4 * 4 + r;
                            if (col > qr) sa[m][n][r] = -1e30f;
                        }
            }

#pragma unroll
            for (int m = 0; m < 2; ++m)
#pragma unroll
                for (int r = 0; r < 4; ++r) {
                    float mx = fmaxf(fmaxf(sa[m][0][r], sa[m][1][r]),
                                     fmaxf(sa[m][2][r], sa[m][3][r]));
#pragma unroll
                    for (int mk = 1; mk <= 8; mk <<= 1) mx = fmaxf(mx, __shfl_xor(mx, mk));
                    const float mn = fmaxf(m_run[m][r], mx);
                    const float alpha = fexp2(m_run[m][r] - mn);
                    m_run[m][r] = mn;
                    float rs = 0.f;
#pragma unroll
                    for (int n = 0; n < 4; ++n) {
                        const float p = fexp2(sa[m][n][r] - mn);
                        sa[m][n][r] = p;
                        rs += p;
                    }
#pragma unroll
                    for (int mk = 1; mk <= 8; mk <<= 1) rs += __shfl_xor(rs, mk);
                    l_run[m][r] = l_run[m][r] * alpha + rs;
#pragma unroll
                    for (int df = 0; df < 8; ++df) o[m][df][r] *= alpha;
                }

#pragma unroll
            for (int m = 0; m < 2; ++m)
#pragma unroll
                for (int n = 0; n < 4; ++n)
#pragma unroll
                    for (int r = 0; r < 4; ++r)
                        Ps[w][(m * 16 + l4 * 4 + r) * 88 + n * 16 + l15] = (bf16)sa[m][n][r];

            bf16x8 pf0[2], pf1[2];
#pragma unroll
            for (int ks = 0; ks < 2; ++ks) {
                pf0[ks] = *(const bf16x8*)(&Ps[w][l15 * 88 + ks * 32 + l4 * 8]);
                pf1[ks] = *(const bf16x8*)(&Ps[w][(16 + l15) * 88 + ks * 32 + l4 * 8]);
            }

            __builtin_amdgcn_s_setprio(1);
#pragma unroll
            for (int df = 0; df < 8; ++df)
#pragma unroll
                for (int ks = 0; ks < 2; ++ks) {
                    const int vrow = df * 16 + l15;
                    const int cc = ks * 4 + l4;
                    const bf16x8 vf =
                        *(const bf16x8*)((const char*)Vs + (vrow << 7) + ((cc ^ (vrow & 7)) << 4));
                    o[0][df] = MFMA16(pf0[ks], vf, o[0][df]);
                    o[1][df] = MFMA16(pf1[ks], vf, o[1][df]);
                }
            __builtin_amdgcn_s_setprio(0);
        }

#pragma unroll
        for (int m = 0; m < 2; ++m)
#pragma unroll
            for (int r = 0; r < 4; ++r) {
                const float inv = 1.f / l_run[m][r];
                const size_t row = (size_t)(b * SS + q0 + w * 32 + m * 16 + l4 * 4 + r);
#pragma unroll
                for (int df = 0; df < 8; ++df)
                    Ob[(row << 12) + h * HD + df * 16 + l15] = (bf16)(o[m][df][r] * inv);
            }
    }
}

// ---------------- launcher ----------------
extern "C" void kernel_launch(void* const* d_in, const int* in_sizes, int n_in,
                              void* d_out, int out_size, void* d_ws, size_t ws_size,
                              hipStream_t stream) {
    const float* x    = (const float*)d_in[0];
    const float* fc   = (const float*)d_in[1];
    const float* wqkv = (const float*)d_in[2];
    const float* wo   = (const float*)d_in[3];

    char* wsp = (char*)d_ws;
    const size_t MB = (size_t)1 << 20;
    bf16* xb    = (bf16*)(wsp);              // 32MB
    bf16* wqkvT = (bf16*)(wsp + 32 * MB);    // 48MB
    bf16* woT   = (bf16*)(wsp + 32 * MB);    // 32MB (aliases wqkvT; written after gemm_qkv)
    bf16* Qb    = (bf16*)(wsp + 80 * MB);    // 32MB
    bf16* Kb    = (bf16*)(wsp + 112 * MB);   //  8MB
    bf16* VTb   = (bf16*)(wsp + 120 * MB);   //  8MB
    bf16* Ab    = (bf16*)(wsp);              // attn out bf16 (aliases xb)
    float* out  = (float*)d_out;

    k_cvt_x<<<8192, 256, 0, stream>>>(x, xb);
    k_tr_cvt<<<dim3(NQKV / 64, DD / 64), 256, 0, stream>>>(wqkv, wqkvT, DD, NQKV);
    k_gemm_qkv<<<dim3(NQKV / 192, (BB * SS) / 256), 512, 0, stream>>>(xb, wqkvT, fc, Qb, Kb, VTb);
    k_tr_cvt<<<dim3(DD / 64, QDIM / 64), 256, 0, stream>>>(wo, woT, QDIM, DD);
    k_attn<<<dim3(8, NH, BB), 256, 0, stream>>>(Qb, Kb, VTb, Ab);
    k_gemm_out<<<dim3(DD / 256, (BB * SS) / 256), 512, 0, stream>>>(Ab, woT, out);
}